// Round 1
// baseline (680.864 us; speedup 1.0000x reference)
//
#include <hip/hip_runtime.h>

// Entmax-1.5 loss, n=4096 rows x d=32000 fp32 logits -> scalar mean loss.
// Root-finding formulation (no sort): tau solves sum clip(x/2 - tau', 0)^2 = 1.
// Work in unshifted halved coords y = x/2; threshold T in [c-1, c-1/sqrt(d)],
// where c = max(y). Newton-from-below (monotone, f convex) + final exact
// quadratic solve over the stabilized support == reference's formula.

#define D          32000
#define NF4        8000      // D/4
#define BLK        1024
#define CAP        8192      // LDS candidate buffer (floats); ~170 expected
#define NEWTON_IT  12

__global__ __launch_bounds__(BLK, 8)
void entmax15_loss_rows(const float* __restrict__ x,
                        const int* __restrict__ tgt,
                        float* __restrict__ out,
                        float inv_n) {
    __shared__ float s_buf[CAP];
    __shared__ float s_red[16];
    __shared__ float s_max;
    __shared__ int   s_cnt;

    const int tid = threadIdx.x;
    const int r   = blockIdx.x;
    const float* row = x + (size_t)r * D;

    if (tid == 0) s_cnt = 0;

    // ---- single HBM pass: 8 coalesced float4 loads into registers ----
    float v[32];
    const float4* row4 = (const float4*)row;
#pragma unroll
    for (int i = 0; i < 7; ++i) {
        float4 t = row4[tid + i * 1024];
        v[4*i+0] = t.x; v[4*i+1] = t.y; v[4*i+2] = t.z; v[4*i+3] = t.w;
    }
    if (tid < NF4 - 7 * 1024) {           // remainder: 832 float4s
        float4 t = row4[tid + 7 * 1024];
        v[28] = t.x; v[29] = t.y; v[30] = t.z; v[31] = t.w;
    } else {
        v[28] = v[29] = v[30] = v[31] = -1e30f;
    }

    // ---- block max ----
    float m = -1e30f;
#pragma unroll
    for (int i = 0; i < 32; ++i) m = fmaxf(m, v[i]);
#pragma unroll
    for (int off = 32; off > 0; off >>= 1) m = fmaxf(m, __shfl_xor(m, off));
    const int lane = tid & 63, wave = tid >> 6;
    if (lane == 0) s_red[wave] = m;
    __syncthreads();
    if (tid < 64) {
        float mm = (lane < 16) ? s_red[lane] : -1e30f;
#pragma unroll
        for (int off = 8; off > 0; off >>= 1) mm = fmaxf(mm, __shfl_xor(mm, off));
        if (lane == 0) s_max = mm;
    }
    __syncthreads();

    const float xmax = s_max;
    const float thr  = xmax - 2.0f;   // v > xmax-2  <=>  y > c-1 >= all support

    // ---- compact candidate set into LDS (store y = v/2) ----
#pragma unroll
    for (int i = 0; i < 32; ++i) {
        if (v[i] > thr) {
            int p = atomicAdd(&s_cnt, 1);
            if (p < CAP) s_buf[p] = 0.5f * v[i];
        }
    }
    __syncthreads();

    if (tid >= 64) return;            // wave 0 finishes the row alone

    const float c    = 0.5f * xmax;
    const float Tcap = c - 0.0055f;   // tau <= c - 1/sqrt(d) always
    int  cnt = s_cnt;
    bool ovf = cnt > CAP;             // impossible for this data; safe fallback

    float T = c - 1.0f;
    for (int it = 0; it <= NEWTON_IT; ++it) {
        float k = 0.f, B = 0.f, A = 0.f;
        if (!ovf) {
            for (int j = lane; j < cnt; j += 64) {
                float y = s_buf[j];
                if (y > T) { k += 1.f; B += y; A = fmaf(y, y, A); }
            }
        } else {
            for (int j = lane; j < D; j += 64) {
                float y = 0.5f * row[j];
                if (y > T) { k += 1.f; B += y; A = fmaf(y, y, A); }
            }
        }
#pragma unroll
        for (int off = 32; off > 0; off >>= 1) {
            k += __shfl_xor(k, off);
            B += __shfl_xor(B, off);
            A += __shfl_xor(A, off);
        }
        if (it < NEWTON_IT) {
            // f(T) = k*T^2 - 2*B*T + A ; f'(T) = -2*(B - k*T)
            float f  = fmaf(fmaf(k, T, -2.f * B), T, A);
            float s1 = B - k * T;
            T = fminf(T + 0.5f * (f - 1.f) / s1, Tcap);
        } else {
            // exact solve over stabilized support (reference formula)
            float mean  = B / k;
            float delta = fmaxf(fmaf(mean, mean, -(A - 1.f) / k), 0.f);
            T = fminf(mean - sqrtf(delta), Tcap);
        }
    }

    // ---- final stats: S15 = sum u^3, Spx = sum u^2 * x  (u = y - T > 0) ----
    float S15 = 0.f, Spx = 0.f;
    if (!ovf) {
        for (int j = lane; j < cnt; j += 64) {
            float y = s_buf[j];
            float u = y - T;
            if (u > 0.f) { float p = u * u; S15 = fmaf(p, u, S15); Spx = fmaf(p, 2.f * y, Spx); }
        }
    } else {
        for (int j = lane; j < D; j += 64) {
            float y = 0.5f * row[j];
            float u = y - T;
            if (u > 0.f) { float p = u * u; S15 = fmaf(p, u, S15); Spx = fmaf(p, 2.f * y, Spx); }
        }
    }
#pragma unroll
    for (int off = 32; off > 0; off >>= 1) {
        S15 += __shfl_xor(S15, off);
        Spx += __shfl_xor(Spx, off);
    }

    if (lane == 0) {
        float xt   = row[tgt[r]];
        float loss = (1.f - S15) * (4.f / 3.f) + Spx - xt;
        atomicAdd(out, loss * inv_n);
    }
}

extern "C" void kernel_launch(void* const* d_in, const int* in_sizes, int n_in,
                              void* d_out, int out_size, void* d_ws, size_t ws_size,
                              hipStream_t stream) {
    const float* xin = (const float*)d_in[0];
    const int*   tgt = (const int*)d_in[1];
    float*       out = (float*)d_out;
    const int n = in_sizes[0] / D;   // 4096 rows

    hipMemsetAsync(out, 0, sizeof(float), stream);
    entmax15_loss_rows<<<n, BLK, 0, stream>>>(xin, tgt, out, 1.0f / (float)n);
}